// Round 12
// baseline (355.067 us; speedup 1.0000x reference)
//
#include <hip/hip_runtime.h>
#include <math.h>

#define IMG_W 128
#define HW 16384
#define NCH 128
#define CSLOT 16777216   // 8*128*16384 elements (h_next slot size)

typedef __attribute__((ext_vector_type(8))) short bf16x8;
typedef __attribute__((ext_vector_type(16))) float f32x16;
typedef __attribute__((ext_vector_type(8))) unsigned short us8;

__device__ __forceinline__ float sigmoidf_(float x) {
    // fast native sigmoid: v_mul+v_exp+v_add+v_rcp (~4 ops vs ~30 for libm)
    return __fdividef(1.0f, 1.0f + __expf(-x));
}

__device__ __forceinline__ unsigned short f2bf(float f) {
    union { float f; unsigned int u; } x; x.f = f;
    unsigned int r = x.u + 0x7fffu + ((x.u >> 16) & 1u);   // RNE
    return (unsigned short)(r >> 16);
}
__device__ __forceinline__ float bf2f(unsigned short s) {
    union { unsigned int u; float f; } x; x.u = ((unsigned int)s) << 16; return x.f;
}

// =====================================================================
// B-data layout (bf16): [b][y 128][g = ch/8][x 128][c = ch%8]
//   dxh:  G=32 (g 0..15 = x-conv channels, g 16..31 = h-conv xh channels)
//   dexc: G=16 ; dinh: G=16
// =====================================================================

// ---------------- x depthwise conv 5x5 ----------------
#define CSX2 804   // 20 rows x 40 cols + 4 pad
__global__ __launch_bounds__(256) void conv_x_kernel(const float* __restrict__ in,
    const float* __restrict__ w, const float* __restrict__ bias,
    unsigned short* __restrict__ dxh)
{
    __shared__ float t[8 * CSX2];
    __shared__ float wsh[208];        // 8*25 + 8 bias
    int xt = blockIdx.x, ys = blockIdx.y, z = blockIdx.z;
    int b = z >> 4, g = z & 15;
    int x0 = xt * 32, y0 = ys * 16;
    int tid = threadIdx.x;

    for (int i = tid; i < 200; i += 256) {
        int c = i / 25, r = i % 25;
        wsh[c * 25 + r] = w[(g * 8 + c) * 25 + r];
    }
    if (tid < 8) wsh[200 + tid] = bias[g * 8 + tid];

    const float* base = in + (size_t)(b * NCH + g * 8) * HW;
    for (int j = tid; j < 1600; j += 256) {      // 8c x 20r x 10k
        int k = j % 10, rc = j / 10;
        int r = rc % 20, c = rc / 20;
        int gy = y0 + r - 2, cb = x0 - 4 + 4 * k;
        float4 v = make_float4(0.f, 0.f, 0.f, 0.f);
        if ((unsigned)gy < 128u && (unsigned)cb <= 124u)
            v = *(const float4*)(base + (size_t)c * HW + gy * IMG_W + cb);
        *(float4*)&t[c * CSX2 + r * 40 + 4 * k] = v;
    }
    __syncthreads();

    int c = tid & 7, txq = (tid >> 3) & 3, ty = tid >> 5;
    int tx = txq * 8;
    const float* tc = &t[c * CSX2];
    float acc[2][8] = {};
#pragma unroll
    for (int rr = 0; rr < 6; ++rr) {
        int R = 2 * ty + rr;
        float win[16];
        *(float4*)&win[0]  = *(const float4*)&tc[R * 40 + tx];
        *(float4*)&win[4]  = *(const float4*)&tc[R * 40 + tx + 4];
        *(float4*)&win[8]  = *(const float4*)&tc[R * 40 + tx + 8];
        *(float4*)&win[12] = *(const float4*)&tc[R * 40 + tx + 12];
#pragma unroll
        for (int p = 0; p < 2; ++p) {
            int u = rr - p;
            if (u >= 0 && u <= 4) {
#pragma unroll
                for (int v = 0; v < 5; ++v) {
                    float wv = wsh[c * 25 + u * 5 + v];
#pragma unroll
                    for (int j = 0; j < 8; ++j) acc[p][j] += win[j + v + 2] * wv;
                }
            }
        }
    }
    float bv = wsh[200 + c];
#pragma unroll
    for (int p = 0; p < 2; ++p) {
        int y = y0 + 2 * ty + p;
        unsigned short* dst = &dxh[(((size_t)(b * 128 + y) * 32 + g) * 128 + x0 + tx) * 8 + c];
#pragma unroll
        for (int j = 0; j < 8; ++j) dst[j * 8] = f2bf(acc[p][j] + bv);
    }
}

// ---------------- fused h depthwise convs: 7x7(exc) + 5x5(xh) + 5x5(inh) ----------------
#define CSH2 884   // 22 rows x 40 cols + 4 pad
__global__ __launch_bounds__(256) void conv_h_kernel(const float* __restrict__ in,
    const float* __restrict__ w7,  const float* __restrict__ b7,
    const float* __restrict__ w5x, const float* __restrict__ b5x,
    const float* __restrict__ w5i, const float* __restrict__ b5i,
    unsigned short* __restrict__ dxh, unsigned short* __restrict__ dexc,
    unsigned short* __restrict__ dinh)
{
    __shared__ float t[8 * CSH2];
    __shared__ float wsh[816];        // 8*(49+25+25) + 24 biases
    int xt = blockIdx.x, ys = blockIdx.y, z = blockIdx.z;
    int b = z >> 4, g = z & 15;
    int x0 = xt * 32, y0 = ys * 16;
    int tid = threadIdx.x;

    for (int i = tid; i < 792; i += 256) {
        int c = i / 99, r = i % 99;
        int ch = g * 8 + c;
        float v;
        if (r < 49)      v = w7[ch * 49 + r];
        else if (r < 74) v = w5x[ch * 25 + r - 49];
        else             v = w5i[ch * 25 + r - 74];
        wsh[i] = v;
    }
    if (tid < 24) {
        int c = tid & 7, m = tid >> 3;
        wsh[792 + tid] = (m == 0) ? b7[g * 8 + c] : (m == 1) ? b5x[g * 8 + c] : b5i[g * 8 + c];
    }

    const float* base = in + (size_t)(b * NCH + g * 8) * HW;
    for (int j = tid; j < 1760; j += 256) {      // 8c x 22r x 10k
        int k = j % 10, rc = j / 10;
        int r = rc % 22, c = rc / 22;
        int gy = y0 + r - 3, cb = x0 - 4 + 4 * k;
        float4 v = make_float4(0.f, 0.f, 0.f, 0.f);
        if ((unsigned)gy < 128u && (unsigned)cb <= 124u)
            v = *(const float4*)(base + (size_t)c * HW + gy * IMG_W + cb);
        *(float4*)&t[c * CSH2 + r * 40 + 4 * k] = v;
    }
    __syncthreads();

    int c = tid & 7, txq = (tid >> 3) & 3, ty = tid >> 5;
    int tx = txq * 8;
    const float* tc = &t[c * CSH2];
    const int W = c * 99;
    float a7[2][8] = {}, ax[2][8] = {}, ai[2][8] = {};
#pragma unroll
    for (int rr = 0; rr < 8; ++rr) {
        int R = 2 * ty + rr;
        float win[16];
        *(float4*)&win[0]  = *(const float4*)&tc[R * 40 + tx];
        *(float4*)&win[4]  = *(const float4*)&tc[R * 40 + tx + 4];
        *(float4*)&win[8]  = *(const float4*)&tc[R * 40 + tx + 8];
        *(float4*)&win[12] = *(const float4*)&tc[R * 40 + tx + 12];
#pragma unroll
        for (int p = 0; p < 2; ++p) {
            int u = rr - p;
            if (u >= 0 && u <= 6) {
#pragma unroll
                for (int v = 0; v < 7; ++v) {
                    float wv = wsh[W + u * 7 + v];
#pragma unroll
                    for (int j = 0; j < 8; ++j) a7[p][j] += win[j + v + 1] * wv;
                }
            }
            int u5 = rr - p - 1;
            if (u5 >= 0 && u5 <= 4) {
#pragma unroll
                for (int v = 0; v < 5; ++v) {
                    float wx = wsh[W + 49 + u5 * 5 + v];
                    float wi = wsh[W + 74 + u5 * 5 + v];
#pragma unroll
                    for (int j = 0; j < 8; ++j) {
                        float e = win[j + v + 2];
                        ax[p][j] += e * wx;
                        ai[p][j] += e * wi;
                    }
                }
            }
        }
    }
    float bE = wsh[792 + c], bX = wsh[800 + c], bI = wsh[808 + c];
#pragma unroll
    for (int p = 0; p < 2; ++p) {
        int y = y0 + 2 * ty + p;
        size_t r16 = ((size_t)(b * 128 + y) * 16 + g) * 128 + x0 + tx;
        unsigned short* dE = &dexc[r16 * 8 + c];
        unsigned short* dI = &dinh[r16 * 8 + c];
        unsigned short* dX = &dxh[(((size_t)(b * 128 + y) * 32 + 16 + g) * 128 + x0 + tx) * 8 + c];
#pragma unroll
        for (int j = 0; j < 8; ++j) {
            dE[j * 8] = f2bf(a7[p][j] + bE);
            dX[j * 8] = f2bf(ax[p][j] + bX);
            dI[j * 8] = f2bf(ai[p][j] + bI);
        }
    }
}

// ---------------- pointwise weight prepack: per-lane fragment-linear A' ----------------
// A'[gcT 4][fi 64][lane 64][c 8] bf16.  fi<48: xh (fi = (c0/64)*12 + ks*3 + m);
// 48..55: exc; 56..63: inh.  k = c0+ks*16+hi*8+c, row = gcT*32+lrow.
__global__ void wconv_kernel(const float* __restrict__ Wxh, const float* __restrict__ Wexc,
                             const float* __restrict__ Winh, unsigned short* __restrict__ A)
{
    int i = blockIdx.x * 256 + threadIdx.x;
    if (i >= 131072) return;
    int c = i & 7, lane = (i >> 3) & 63, fi = (i >> 9) & 63, gcT = i >> 15;
    int hi = lane >> 5, lrow = lane & 31, row = gcT * 32 + lrow;
    float v;
    if (fi < 48) {
        int c0 = (fi / 12) * 64, r = fi % 12, ks = r / 3, m = r % 3;
        v = Wxh[(size_t)(m * 128 + row) * 256 + c0 + ks * 16 + hi * 8 + c];
    } else if (fi < 56) {
        int j = fi - 48, c0 = (j >> 2) * 64, ks = j & 3;
        v = Wexc[(size_t)row * 128 + c0 + ks * 16 + hi * 8 + c];
    } else {
        int j = fi - 56, c0 = (j >> 2) * 64, ks = j & 3;
        v = Winh[(size_t)row * 128 + c0 + ks * 16 + hi * 8 + c];
    }
    A[i] = f2bf(v);
}

// ---------------- MFMA gate kernel: A staged once in LDS, B register-streamed ----------------
__global__ __launch_bounds__(256) void gate_kernel(
                            const unsigned short* __restrict__ dxh,
                            const unsigned short* __restrict__ dexc,
                            const unsigned short* __restrict__ dinh,
                            const unsigned short* __restrict__ Afrag,
                            const float* __restrict__ bxh,
                            const float* __restrict__ bexc,
                            const float* __restrict__ binh,
                            const float* __restrict__ cin,
                            float* __restrict__ out,
                            unsigned short* __restrict__ obuf,
                            float* __restrict__ partials)
{
    __shared__ us8 Ash[4096];    // 64 KB: this block's A'[gcT] slice
    __shared__ float rbuf[8];
    int d = blockIdx.x;
    int orig = (d & 7) * 512 + (d >> 3);
    int b = orig >> 9, y = (orig >> 2) & 127, gcT = orig & 3;
    int gc0 = gcT * 32;
    int tid = threadIdx.x, lane = tid & 63, w = tid >> 6;
    int hi = lane >> 5, lrow = lane & 31;
    int pxl = (w << 5) + lrow;

    // stage A once per block (all 4 waves previously loaded identical data)
    {
        const us8* Ag = (const us8*)Afrag + (size_t)gcT * 4096;
        for (int i = tid; i < 4096; i += 256) Ash[i] = Ag[i];
    }
    __syncthreads();

    f32x16 accF = {}, accG = {}, accO = {}, accE = {}, accI = {};

    const us8* Ab = Ash + lane;                                           // + fi*64
    const us8* Bx = (const us8*)dxh  + ((size_t)(b * 128 + y) * 32) * 128 + pxl;
    const us8* Be = (const us8*)dexc + ((size_t)(b * 128 + y) * 16) * 128 + pxl;
    const us8* Bi = (const us8*)dinh + ((size_t)(b * 128 + y) * 16) * 128 + pxl;

    for (int c0i = 0; c0i < 4; ++c0i) {
#pragma unroll
        for (int ks = 0; ks < 4; ++ks) {
            int gidx = c0i * 8 + ks * 2 + hi;
            bf16x8 bf = *(const bf16x8*)(Bx + gidx * 128);
            int fi = c0i * 12 + ks * 3;
            bf16x8 aF = *(const bf16x8*)(Ab + fi * 64);
            bf16x8 aG = *(const bf16x8*)(Ab + (fi + 1) * 64);
            bf16x8 aO = *(const bf16x8*)(Ab + (fi + 2) * 64);
            accF = __builtin_amdgcn_mfma_f32_32x32x16_bf16(aF, bf, accF, 0, 0, 0);
            accG = __builtin_amdgcn_mfma_f32_32x32x16_bf16(aG, bf, accG, 0, 0, 0);
            accO = __builtin_amdgcn_mfma_f32_32x32x16_bf16(aO, bf, accO, 0, 0, 0);
        }
    }
    for (int c0i = 0; c0i < 2; ++c0i) {
#pragma unroll
        for (int ks = 0; ks < 4; ++ks) {
            int gidx = c0i * 8 + ks * 2 + hi;
            bf16x8 bf = *(const bf16x8*)(Be + gidx * 128);
            bf16x8 aE = *(const bf16x8*)(Ab + (48 + c0i * 4 + ks) * 64);
            accE = __builtin_amdgcn_mfma_f32_32x32x16_bf16(aE, bf, accE, 0, 0, 0);
        }
    }
    for (int c0i = 0; c0i < 2; ++c0i) {
#pragma unroll
        for (int ks = 0; ks < 4; ++ks) {
            int gidx = c0i * 8 + ks * 2 + hi;
            bf16x8 bf = *(const bf16x8*)(Bi + gidx * 128);
            bf16x8 aI = *(const bf16x8*)(Ab + (56 + c0i * 4 + ks) * 64);
            accI = __builtin_amdgcn_mfma_f32_32x32x16_bf16(aI, bf, accI, 0, 0, 0);
        }
    }

    float lsum = 0.f, lsq = 0.f;
#pragma unroll
    for (int r = 0; r < 16; ++r) {
        int row = (r & 3) + 8 * (r >> 2) + 4 * hi;   // verified 32x32 C/D map
        int gc = gc0 + row;
        size_t idx = ((size_t)(b * NCH + gc)) * HW + y * IMG_W + pxl;
        float f    = sigmoidf_(accF[r] + bxh[gc]);
        float o    = sigmoidf_(accO[r] + bxh[gc + 256]);
        float xhor = fmaxf(accG[r] + bxh[gc + 128], 0.f);
        float g    = sigmoidf_(accI[r] + binh[gc]) * (xhor + sigmoidf_(accE[r] + bexc[gc]));
        float cn   = f * cin[idx] + (1.f - f) * g;
        out[CSLOT + idx] = cn;
        obuf[idx] = f2bf(o);
        lsum += cn; lsq += cn * cn;
    }

#pragma unroll
    for (int off = 32; off; off >>= 1) {
        lsum += __shfl_down(lsum, off);
        lsq  += __shfl_down(lsq, off);
    }
    if ((tid & 63) == 0) { rbuf[w * 2] = lsum; rbuf[w * 2 + 1] = lsq; }
    __syncthreads();
    if (tid == 0) {
        float s = rbuf[0] + rbuf[2] + rbuf[4] + rbuf[6];
        float q = rbuf[1] + rbuf[3] + rbuf[5] + rbuf[7];
        int blin = b * 512 + gcT * 128 + y;
        partials[blin * 2]     = s;
        partials[blin * 2 + 1] = q;
    }
}

// ---------------- per-sample LN statistics ----------------
__global__ void stats_kernel(const float* __restrict__ partials, float* __restrict__ stats)
{
    int b = blockIdx.x;
    int tid = threadIdx.x;
    float s = 0.f, q = 0.f;
    for (int i = tid; i < 512; i += 256) {
        s += partials[(b * 512 + i) * 2];
        q += partials[(b * 512 + i) * 2 + 1];
    }
#pragma unroll
    for (int off = 32; off; off >>= 1) {
        s += __shfl_down(s, off);
        q += __shfl_down(q, off);
    }
    __shared__ float rb[8];
    int wid = tid >> 6;
    if ((tid & 63) == 0) { rb[wid * 2] = s; rb[wid * 2 + 1] = q; }
    __syncthreads();
    if (tid == 0) {
        float S = rb[0] + rb[2] + rb[4] + rb[6];
        float Q = rb[1] + rb[3] + rb[5] + rb[7];
        const float N = 2097152.0f;
        float mean = S / N;
        float var = Q / N - mean * mean;
        stats[b * 2] = mean;
        stats[b * 2 + 1] = rsqrtf(var + 1e-5f);
    }
}

// ---------------- finalize: h_next = o * relu((c_next-mean)*rstd) ----------------
__global__ void final_kernel(float* __restrict__ out, const unsigned short* __restrict__ obuf,
                             const float* __restrict__ stats)
{
    const int n8 = CSLOT / 8;
    const int per_b = 2097152 / 8;
    for (int i = blockIdx.x * blockDim.x + threadIdx.x; i < n8; i += gridDim.x * blockDim.x) {
        int b = i / per_b;
        float mean = stats[b * 2], rstd = stats[b * 2 + 1];
        us8 o8 = *(const us8*)&obuf[(size_t)i * 8];
        float4 c0 = ((const float4*)out)[CSLOT / 4 + i * 2];
        float4 c1 = ((const float4*)out)[CSLOT / 4 + i * 2 + 1];
        float4 h0, h1;
        h0.x = bf2f(o8[0]) * fmaxf((c0.x - mean) * rstd, 0.f);
        h0.y = bf2f(o8[1]) * fmaxf((c0.y - mean) * rstd, 0.f);
        h0.z = bf2f(o8[2]) * fmaxf((c0.z - mean) * rstd, 0.f);
        h0.w = bf2f(o8[3]) * fmaxf((c0.w - mean) * rstd, 0.f);
        h1.x = bf2f(o8[4]) * fmaxf((c1.x - mean) * rstd, 0.f);
        h1.y = bf2f(o8[5]) * fmaxf((c1.y - mean) * rstd, 0.f);
        h1.z = bf2f(o8[6]) * fmaxf((c1.z - mean) * rstd, 0.f);
        h1.w = bf2f(o8[7]) * fmaxf((c1.w - mean) * rstd, 0.f);
        ((float4*)out)[i * 2]     = h0;
        ((float4*)out)[i * 2 + 1] = h1;
    }
}

extern "C" void kernel_launch(void* const* d_in, const int* in_sizes, int n_in,
                              void* d_out, int out_size, void* d_ws, size_t ws_size,
                              hipStream_t stream)
{
    const float* x        = (const float*)d_in[0];
    const float* h        = (const float*)d_in[1];
    const float* c        = (const float*)d_in[2];
    const float* w_xh_dw  = (const float*)d_in[3];
    const float* b_xh_dw  = (const float*)d_in[4];
    const float* w_xh_pw  = (const float*)d_in[5];
    const float* b_xh_pw  = (const float*)d_in[6];
    const float* w_exc_dw = (const float*)d_in[7];
    const float* b_exc_dw = (const float*)d_in[8];
    const float* w_exc_pw = (const float*)d_in[9];
    const float* b_exc_pw = (const float*)d_in[10];
    const float* w_inh_dw = (const float*)d_in[11];
    const float* b_inh_dw = (const float*)d_in[12];
    const float* w_inh_pw = (const float*)d_in[13];
    const float* b_inh_pw = (const float*)d_in[14];

    float* out = (float*)d_out;
    unsigned short* wsu = (unsigned short*)d_ws;

    unsigned short* dxh   = wsu;                      // 33,554,432 u16
    unsigned short* dexc  = wsu + 33554432;           // 16,777,216
    unsigned short* dinh  = wsu + 50331648;           // 16,777,216
    unsigned short* Afrag = wsu + 67108864;           // 131,072
    unsigned short* obuf  = wsu + 67239936;           // 16,777,216
    float* partials = (float*)(wsu + 84017152);       // 8,192 floats
    float* stats    = partials + 8192;                // 16 floats

    wconv_kernel<<<dim3(512), dim3(256), 0, stream>>>(w_xh_pw, w_exc_pw, w_inh_pw, Afrag);

    conv_x_kernel<<<dim3(4, 8, 128), dim3(256), 0, stream>>>(x, w_xh_dw, b_xh_dw, dxh);
    conv_h_kernel<<<dim3(4, 8, 128), dim3(256), 0, stream>>>(
        h, w_exc_dw, b_exc_dw, w_xh_dw + 128 * 25, b_xh_dw + 128, w_inh_dw, b_inh_dw,
        dxh, dexc, dinh);

    gate_kernel<<<dim3(4096), dim3(256), 0, stream>>>(
        dxh, dexc, dinh, Afrag, b_xh_pw, b_exc_pw, b_inh_pw, c, out, obuf, partials);

    stats_kernel<<<dim3(8), dim3(256), 0, stream>>>(partials, stats);
    final_kernel<<<dim3(2048), dim3(256), 0, stream>>>(out, obuf, stats);
}

// Round 13
// 322.021 us; speedup vs baseline: 1.1026x; 1.1026x over previous
//
#include <hip/hip_runtime.h>
#include <math.h>

#define IMG_W 128
#define HW 16384
#define NCH 128
#define CSLOT 16777216   // 8*128*16384 elements (h_next slot size)

typedef __attribute__((ext_vector_type(8))) short bf16x8;
typedef __attribute__((ext_vector_type(16))) float f32x16;
typedef __attribute__((ext_vector_type(8))) unsigned short us8;

__device__ __forceinline__ float sigmoidf_(float x) {
    // fast native sigmoid: v_mul+v_exp+v_add+v_rcp (~4 ops vs ~30 for libm)
    return __fdividef(1.0f, 1.0f + __expf(-x));
}

__device__ __forceinline__ unsigned short f2bf(float f) {
    union { float f; unsigned int u; } x; x.f = f;
    unsigned int r = x.u + 0x7fffu + ((x.u >> 16) & 1u);   // RNE
    return (unsigned short)(r >> 16);
}
__device__ __forceinline__ float bf2f(unsigned short s) {
    union { unsigned int u; float f; } x; x.u = ((unsigned int)s) << 16; return x.f;
}

// =====================================================================
// B-data layout (bf16): [b][y 128][g = ch/8][x 128][c = ch%8]
//   dxh:  G=32 (g 0..15 = x-conv channels, g 16..31 = h-conv xh channels)
//   dexc: G=16 ; dinh: G=16
// =====================================================================

// ---------------- x depthwise conv 5x5 ----------------
#define CSX2 804   // 20 rows x 40 cols + 4 pad
__global__ __launch_bounds__(256) void conv_x_kernel(const float* __restrict__ in,
    const float* __restrict__ w, const float* __restrict__ bias,
    unsigned short* __restrict__ dxh)
{
    __shared__ float t[8 * CSX2];
    __shared__ float wsh[208];        // 8*25 + 8 bias
    int xt = blockIdx.x, ys = blockIdx.y, z = blockIdx.z;
    int b = z >> 4, g = z & 15;
    int x0 = xt * 32, y0 = ys * 16;
    int tid = threadIdx.x;

    for (int i = tid; i < 200; i += 256) {
        int c = i / 25, r = i % 25;
        wsh[c * 25 + r] = w[(g * 8 + c) * 25 + r];
    }
    if (tid < 8) wsh[200 + tid] = bias[g * 8 + tid];

    const float* base = in + (size_t)(b * NCH + g * 8) * HW;
    for (int j = tid; j < 1600; j += 256) {      // 8c x 20r x 10k
        int k = j % 10, rc = j / 10;
        int r = rc % 20, c = rc / 20;
        int gy = y0 + r - 2, cb = x0 - 4 + 4 * k;
        float4 v = make_float4(0.f, 0.f, 0.f, 0.f);
        if ((unsigned)gy < 128u && (unsigned)cb <= 124u)
            v = *(const float4*)(base + (size_t)c * HW + gy * IMG_W + cb);
        *(float4*)&t[c * CSX2 + r * 40 + 4 * k] = v;
    }
    __syncthreads();

    int c = tid & 7, txq = (tid >> 3) & 3, ty = tid >> 5;
    int tx = txq * 8;
    const float* tc = &t[c * CSX2];
    float acc[2][8] = {};
#pragma unroll
    for (int rr = 0; rr < 6; ++rr) {
        int R = 2 * ty + rr;
        float win[16];
        *(float4*)&win[0]  = *(const float4*)&tc[R * 40 + tx];
        *(float4*)&win[4]  = *(const float4*)&tc[R * 40 + tx + 4];
        *(float4*)&win[8]  = *(const float4*)&tc[R * 40 + tx + 8];
        *(float4*)&win[12] = *(const float4*)&tc[R * 40 + tx + 12];
#pragma unroll
        for (int p = 0; p < 2; ++p) {
            int u = rr - p;
            if (u >= 0 && u <= 4) {
#pragma unroll
                for (int v = 0; v < 5; ++v) {
                    float wv = wsh[c * 25 + u * 5 + v];
#pragma unroll
                    for (int j = 0; j < 8; ++j) acc[p][j] += win[j + v + 2] * wv;
                }
            }
        }
    }
    float bv = wsh[200 + c];
#pragma unroll
    for (int p = 0; p < 2; ++p) {
        int y = y0 + 2 * ty + p;
        unsigned short* dst = &dxh[(((size_t)(b * 128 + y) * 32 + g) * 128 + x0 + tx) * 8 + c];
#pragma unroll
        for (int j = 0; j < 8; ++j) dst[j * 8] = f2bf(acc[p][j] + bv);
    }
}

// ---------------- fused h depthwise convs: 7x7(exc) + 5x5(xh) + 5x5(inh) ----------------
#define CSH2 884   // 22 rows x 40 cols + 4 pad
__global__ __launch_bounds__(256) void conv_h_kernel(const float* __restrict__ in,
    const float* __restrict__ w7,  const float* __restrict__ b7,
    const float* __restrict__ w5x, const float* __restrict__ b5x,
    const float* __restrict__ w5i, const float* __restrict__ b5i,
    unsigned short* __restrict__ dxh, unsigned short* __restrict__ dexc,
    unsigned short* __restrict__ dinh)
{
    __shared__ float t[8 * CSH2];
    __shared__ float wsh[816];        // 8*(49+25+25) + 24 biases
    int xt = blockIdx.x, ys = blockIdx.y, z = blockIdx.z;
    int b = z >> 4, g = z & 15;
    int x0 = xt * 32, y0 = ys * 16;
    int tid = threadIdx.x;

    for (int i = tid; i < 792; i += 256) {
        int c = i / 99, r = i % 99;
        int ch = g * 8 + c;
        float v;
        if (r < 49)      v = w7[ch * 49 + r];
        else if (r < 74) v = w5x[ch * 25 + r - 49];
        else             v = w5i[ch * 25 + r - 74];
        wsh[i] = v;
    }
    if (tid < 24) {
        int c = tid & 7, m = tid >> 3;
        wsh[792 + tid] = (m == 0) ? b7[g * 8 + c] : (m == 1) ? b5x[g * 8 + c] : b5i[g * 8 + c];
    }

    const float* base = in + (size_t)(b * NCH + g * 8) * HW;
    for (int j = tid; j < 1760; j += 256) {      // 8c x 22r x 10k
        int k = j % 10, rc = j / 10;
        int r = rc % 22, c = rc / 22;
        int gy = y0 + r - 3, cb = x0 - 4 + 4 * k;
        float4 v = make_float4(0.f, 0.f, 0.f, 0.f);
        if ((unsigned)gy < 128u && (unsigned)cb <= 124u)
            v = *(const float4*)(base + (size_t)c * HW + gy * IMG_W + cb);
        *(float4*)&t[c * CSH2 + r * 40 + 4 * k] = v;
    }
    __syncthreads();

    int c = tid & 7, txq = (tid >> 3) & 3, ty = tid >> 5;
    int tx = txq * 8;
    const float* tc = &t[c * CSH2];
    const int W = c * 99;
    float a7[2][8] = {}, ax[2][8] = {}, ai[2][8] = {};
#pragma unroll
    for (int rr = 0; rr < 8; ++rr) {
        int R = 2 * ty + rr;
        float win[16];
        *(float4*)&win[0]  = *(const float4*)&tc[R * 40 + tx];
        *(float4*)&win[4]  = *(const float4*)&tc[R * 40 + tx + 4];
        *(float4*)&win[8]  = *(const float4*)&tc[R * 40 + tx + 8];
        *(float4*)&win[12] = *(const float4*)&tc[R * 40 + tx + 12];
#pragma unroll
        for (int p = 0; p < 2; ++p) {
            int u = rr - p;
            if (u >= 0 && u <= 6) {
#pragma unroll
                for (int v = 0; v < 7; ++v) {
                    float wv = wsh[W + u * 7 + v];
#pragma unroll
                    for (int j = 0; j < 8; ++j) a7[p][j] += win[j + v + 1] * wv;
                }
            }
            int u5 = rr - p - 1;
            if (u5 >= 0 && u5 <= 4) {
#pragma unroll
                for (int v = 0; v < 5; ++v) {
                    float wx = wsh[W + 49 + u5 * 5 + v];
                    float wi = wsh[W + 74 + u5 * 5 + v];
#pragma unroll
                    for (int j = 0; j < 8; ++j) {
                        float e = win[j + v + 2];
                        ax[p][j] += e * wx;
                        ai[p][j] += e * wi;
                    }
                }
            }
        }
    }
    float bE = wsh[792 + c], bX = wsh[800 + c], bI = wsh[808 + c];
#pragma unroll
    for (int p = 0; p < 2; ++p) {
        int y = y0 + 2 * ty + p;
        size_t r16 = ((size_t)(b * 128 + y) * 16 + g) * 128 + x0 + tx;
        unsigned short* dE = &dexc[r16 * 8 + c];
        unsigned short* dI = &dinh[r16 * 8 + c];
        unsigned short* dX = &dxh[(((size_t)(b * 128 + y) * 32 + 16 + g) * 128 + x0 + tx) * 8 + c];
#pragma unroll
        for (int j = 0; j < 8; ++j) {
            dE[j * 8] = f2bf(a7[p][j] + bE);
            dX[j * 8] = f2bf(ax[p][j] + bX);
            dI[j * 8] = f2bf(ai[p][j] + bI);
        }
    }
}

// ---------------- pointwise weight prepack: per-lane fragment-linear A' ----------------
// A'[gcT 4][fi 64][lane 64][c 8] bf16.  fi<48: xh (fi = (c0/64)*12 + ks*3 + m);
// 48..55: exc; 56..63: inh.  k = c0+ks*16+hi*8+c, row = gcT*32+lrow.
__global__ void wconv_kernel(const float* __restrict__ Wxh, const float* __restrict__ Wexc,
                             const float* __restrict__ Winh, unsigned short* __restrict__ A)
{
    int i = blockIdx.x * 256 + threadIdx.x;
    if (i >= 131072) return;
    int c = i & 7, lane = (i >> 3) & 63, fi = (i >> 9) & 63, gcT = i >> 15;
    int hi = lane >> 5, lrow = lane & 31, row = gcT * 32 + lrow;
    float v;
    if (fi < 48) {
        int c0 = (fi / 12) * 64, r = fi % 12, ks = r / 3, m = r % 3;
        v = Wxh[(size_t)(m * 128 + row) * 256 + c0 + ks * 16 + hi * 8 + c];
    } else if (fi < 56) {
        int j = fi - 48, c0 = (j >> 2) * 64, ks = j & 3;
        v = Wexc[(size_t)row * 128 + c0 + ks * 16 + hi * 8 + c];
    } else {
        int j = fi - 56, c0 = (j >> 2) * 64, ks = j & 3;
        v = Winh[(size_t)row * 128 + c0 + ks * 16 + hi * 8 + c];
    }
    A[i] = f2bf(v);
}

// ---------------- MFMA gate kernel: 512 threads, 2 y-rows, A in LDS, B prefetch pipeline ----------------
__global__ __launch_bounds__(512) void gate_kernel(
                            const unsigned short* __restrict__ dxh,
                            const unsigned short* __restrict__ dexc,
                            const unsigned short* __restrict__ dinh,
                            const unsigned short* __restrict__ Afrag,
                            const float* __restrict__ bxh,
                            const float* __restrict__ bexc,
                            const float* __restrict__ binh,
                            const float* __restrict__ cin,
                            float* __restrict__ out,
                            unsigned short* __restrict__ obuf,
                            float* __restrict__ partials)
{
    __shared__ us8 Ash[4096];    // 64 KB: this block's A'[gcT] slice
    __shared__ float rbuf[16];
    int d = blockIdx.x;
    int orig = (d & 7) * 256 + (d >> 3);     // 2048 blocks, XCD swizzle
    int b = orig >> 8, yp = (orig >> 2) & 63, gcT = orig & 3;
    int gc0 = gcT * 32;
    int tid = threadIdx.x, lane = tid & 63, w = tid >> 6;
    int yw = w >> 2, wq = w & 3;
    int y = yp * 2 + yw;
    int hi = lane >> 5, lrow = lane & 31;
    int pxl = (wq << 5) + lrow;

    // stage A once per block (amortized over 2 y-rows)
    {
        const us8* Ag = (const us8*)Afrag + (size_t)gcT * 4096;
        for (int i = tid; i < 4096; i += 512) Ash[i] = Ag[i];
    }
    __syncthreads();

    f32x16 accF = {}, accG = {}, accO = {}, accE = {}, accI = {};

    const us8* Ab = Ash + lane;                                           // + fi*64
    const us8* Bx = (const us8*)dxh  + ((size_t)(b * 128 + y) * 32) * 128 + pxl;
    const us8* Be = (const us8*)dexc + ((size_t)(b * 128 + y) * 16) * 128 + pxl;
    const us8* Bi = (const us8*)dinh + ((size_t)(b * 128 + y) * 16) * 128 + pxl;

    bf16x8 p0, p1, p2, p3, q0, q1, q2, q3;   // two prefetch sets

#define LD4(s0, s1, s2, s3, Bp, ci) \
    s0 = *(const bf16x8*)((Bp) + ((ci) * 8 + 0 + hi) * 128); \
    s1 = *(const bf16x8*)((Bp) + ((ci) * 8 + 2 + hi) * 128); \
    s2 = *(const bf16x8*)((Bp) + ((ci) * 8 + 4 + hi) * 128); \
    s3 = *(const bf16x8*)((Bp) + ((ci) * 8 + 6 + hi) * 128);
#define AB(fi) (*(const bf16x8*)(Ab + (fi) * 64))
#define MF(a, bb, acc) acc = __builtin_amdgcn_mfma_f32_32x32x16_bf16(a, bb, acc, 0, 0, 0)
#define XH(s0, s1, s2, s3, ci) \
    MF(AB((ci)*12 + 0), s0, accF); MF(AB((ci)*12 + 1), s0, accG); MF(AB((ci)*12 + 2), s0, accO); \
    MF(AB((ci)*12 + 3), s1, accF); MF(AB((ci)*12 + 4), s1, accG); MF(AB((ci)*12 + 5), s1, accO); \
    MF(AB((ci)*12 + 6), s2, accF); MF(AB((ci)*12 + 7), s2, accG); MF(AB((ci)*12 + 8), s2, accO); \
    MF(AB((ci)*12 + 9), s3, accF); MF(AB((ci)*12 +10), s3, accG); MF(AB((ci)*12 +11), s3, accO);
#define EXC(s0, s1, s2, s3, ci) \
    MF(AB(48 + (ci)*4 + 0), s0, accE); MF(AB(48 + (ci)*4 + 1), s1, accE); \
    MF(AB(48 + (ci)*4 + 2), s2, accE); MF(AB(48 + (ci)*4 + 3), s3, accE);
#define INH(s0, s1, s2, s3, ci) \
    MF(AB(56 + (ci)*4 + 0), s0, accI); MF(AB(56 + (ci)*4 + 1), s1, accI); \
    MF(AB(56 + (ci)*4 + 2), s2, accI); MF(AB(56 + (ci)*4 + 3), s3, accI);

    // software-pipelined: chunk k+1's B loads issue before chunk k's MFMAs
    LD4(p0, p1, p2, p3, Bx, 0)
    LD4(q0, q1, q2, q3, Bx, 1)  XH(p0, p1, p2, p3, 0)
    LD4(p0, p1, p2, p3, Bx, 2)  XH(q0, q1, q2, q3, 1)
    LD4(q0, q1, q2, q3, Bx, 3)  XH(p0, p1, p2, p3, 2)
    LD4(p0, p1, p2, p3, Be, 0)  XH(q0, q1, q2, q3, 3)
    LD4(q0, q1, q2, q3, Be, 1)  EXC(p0, p1, p2, p3, 0)
    LD4(p0, p1, p2, p3, Bi, 0)  EXC(q0, q1, q2, q3, 1)
    LD4(q0, q1, q2, q3, Bi, 1)  INH(p0, p1, p2, p3, 0)
    INH(q0, q1, q2, q3, 1)

    float lsum = 0.f, lsq = 0.f;
#pragma unroll
    for (int r = 0; r < 16; ++r) {
        int row = (r & 3) + 8 * (r >> 2) + 4 * hi;   // verified 32x32 C/D map
        int gc = gc0 + row;
        size_t idx = ((size_t)(b * NCH + gc)) * HW + y * IMG_W + pxl;
        float f    = sigmoidf_(accF[r] + bxh[gc]);
        float o    = sigmoidf_(accO[r] + bxh[gc + 256]);
        float xhor = fmaxf(accG[r] + bxh[gc + 128], 0.f);
        float g    = sigmoidf_(accI[r] + binh[gc]) * (xhor + sigmoidf_(accE[r] + bexc[gc]));
        float cn   = f * cin[idx] + (1.f - f) * g;
        out[CSLOT + idx] = cn;
        obuf[idx] = f2bf(o);
        lsum += cn; lsq += cn * cn;
    }

#pragma unroll
    for (int off = 32; off; off >>= 1) {
        lsum += __shfl_down(lsum, off);
        lsq  += __shfl_down(lsq, off);
    }
    if ((tid & 63) == 0) { rbuf[w * 2] = lsum; rbuf[w * 2 + 1] = lsq; }
    __syncthreads();
    if (tid == 0) {
        int blin = b * 512 + gcT * 128 + yp * 2;
        partials[blin * 2]     = rbuf[0] + rbuf[2] + rbuf[4] + rbuf[6];
        partials[blin * 2 + 1] = rbuf[1] + rbuf[3] + rbuf[5] + rbuf[7];
        partials[blin * 2 + 2] = rbuf[8] + rbuf[10] + rbuf[12] + rbuf[14];
        partials[blin * 2 + 3] = rbuf[9] + rbuf[11] + rbuf[13] + rbuf[15];
    }
}

// ---------------- per-sample LN statistics ----------------
__global__ void stats_kernel(const float* __restrict__ partials, float* __restrict__ stats)
{
    int b = blockIdx.x;
    int tid = threadIdx.x;
    float s = 0.f, q = 0.f;
    for (int i = tid; i < 512; i += 256) {
        s += partials[(b * 512 + i) * 2];
        q += partials[(b * 512 + i) * 2 + 1];
    }
#pragma unroll
    for (int off = 32; off; off >>= 1) {
        s += __shfl_down(s, off);
        q += __shfl_down(q, off);
    }
    __shared__ float rb[8];
    int wid = tid >> 6;
    if ((tid & 63) == 0) { rb[wid * 2] = s; rb[wid * 2 + 1] = q; }
    __syncthreads();
    if (tid == 0) {
        float S = rb[0] + rb[2] + rb[4] + rb[6];
        float Q = rb[1] + rb[3] + rb[5] + rb[7];
        const float N = 2097152.0f;
        float mean = S / N;
        float var = Q / N - mean * mean;
        stats[b * 2] = mean;
        stats[b * 2 + 1] = rsqrtf(var + 1e-5f);
    }
}

// ---------------- finalize: h_next = o * relu((c_next-mean)*rstd) ----------------
__global__ void final_kernel(float* __restrict__ out, const unsigned short* __restrict__ obuf,
                             const float* __restrict__ stats)
{
    const int n8 = CSLOT / 8;
    const int per_b = 2097152 / 8;
    for (int i = blockIdx.x * blockDim.x + threadIdx.x; i < n8; i += gridDim.x * blockDim.x) {
        int b = i / per_b;
        float mean = stats[b * 2], rstd = stats[b * 2 + 1];
        us8 o8 = *(const us8*)&obuf[(size_t)i * 8];
        float4 c0 = ((const float4*)out)[CSLOT / 4 + i * 2];
        float4 c1 = ((const float4*)out)[CSLOT / 4 + i * 2 + 1];
        float4 h0, h1;
        h0.x = bf2f(o8[0]) * fmaxf((c0.x - mean) * rstd, 0.f);
        h0.y = bf2f(o8[1]) * fmaxf((c0.y - mean) * rstd, 0.f);
        h0.z = bf2f(o8[2]) * fmaxf((c0.z - mean) * rstd, 0.f);
        h0.w = bf2f(o8[3]) * fmaxf((c0.w - mean) * rstd, 0.f);
        h1.x = bf2f(o8[4]) * fmaxf((c1.x - mean) * rstd, 0.f);
        h1.y = bf2f(o8[5]) * fmaxf((c1.y - mean) * rstd, 0.f);
        h1.z = bf2f(o8[6]) * fmaxf((c1.z - mean) * rstd, 0.f);
        h1.w = bf2f(o8[7]) * fmaxf((c1.w - mean) * rstd, 0.f);
        ((float4*)out)[i * 2]     = h0;
        ((float4*)out)[i * 2 + 1] = h1;
    }
}

extern "C" void kernel_launch(void* const* d_in, const int* in_sizes, int n_in,
                              void* d_out, int out_size, void* d_ws, size_t ws_size,
                              hipStream_t stream)
{
    const float* x        = (const float*)d_in[0];
    const float* h        = (const float*)d_in[1];
    const float* c        = (const float*)d_in[2];
    const float* w_xh_dw  = (const float*)d_in[3];
    const float* b_xh_dw  = (const float*)d_in[4];
    const float* w_xh_pw  = (const float*)d_in[5];
    const float* b_xh_pw  = (const float*)d_in[6];
    const float* w_exc_dw = (const float*)d_in[7];
    const float* b_exc_dw = (const float*)d_in[8];
    const float* w_exc_pw = (const float*)d_in[9];
    const float* b_exc_pw = (const float*)d_in[10];
    const float* w_inh_dw = (const float*)d_in[11];
    const float* b_inh_dw = (const float*)d_in[12];
    const float* w_inh_pw = (const float*)d_in[13];
    const float* b_inh_pw = (const float*)d_in[14];

    float* out = (float*)d_out;
    unsigned short* wsu = (unsigned short*)d_ws;

    unsigned short* dxh   = wsu;                      // 33,554,432 u16
    unsigned short* dexc  = wsu + 33554432;           // 16,777,216
    unsigned short* dinh  = wsu + 50331648;           // 16,777,216
    unsigned short* Afrag = wsu + 67108864;           // 131,072
    unsigned short* obuf  = wsu + 67239936;           // 16,777,216
    float* partials = (float*)(wsu + 84017152);       // 8,192 floats
    float* stats    = partials + 8192;                // 16 floats

    wconv_kernel<<<dim3(512), dim3(256), 0, stream>>>(w_xh_pw, w_exc_pw, w_inh_pw, Afrag);

    conv_x_kernel<<<dim3(4, 8, 128), dim3(256), 0, stream>>>(x, w_xh_dw, b_xh_dw, dxh);
    conv_h_kernel<<<dim3(4, 8, 128), dim3(256), 0, stream>>>(
        h, w_exc_dw, b_exc_dw, w_xh_dw + 128 * 25, b_xh_dw + 128, w_inh_dw, b_inh_dw,
        dxh, dexc, dinh);

    gate_kernel<<<dim3(2048), dim3(512), 0, stream>>>(
        dxh, dexc, dinh, Afrag, b_xh_pw, b_exc_pw, b_inh_pw, c, out, obuf, partials);

    stats_kernel<<<dim3(8), dim3(256), 0, stream>>>(partials, stats);
    final_kernel<<<dim3(2048), dim3(256), 0, stream>>>(out, obuf, stats);
}